// Round 9
// baseline (3089.690 us; speedup 1.0000x reference)
//
#include <hip/hip_runtime.h>

typedef unsigned short u16;
typedef __attribute__((ext_vector_type(8))) short s8v;
typedef __attribute__((ext_vector_type(4))) float f4v;

#define L_DIM 1024
#define N_DIM 16384
#define R_DIM 128
#define PEN  -10000.0f
#define SCAP 3072

__device__ __forceinline__ f4v mfma16(s8v a, s8v b, f4v c) {
    return __builtin_amdgcn_mfma_f32_16x16x32_bf16(a, b, c, 0, 0, 0);
}
__device__ __forceinline__ float b2f(u16 x) { return __uint_as_float(((unsigned)x) << 16); }
__device__ __forceinline__ u16 f2bf(float f) {
    unsigned u = __float_as_uint(f);
    unsigned r = (u + 0x7FFFu + ((u >> 16) & 1u)) >> 16;
    return (u16)r;
}
__device__ __forceinline__ unsigned fkey(float f) {
    unsigned u = __float_as_uint(f);
    return (u & 0x80000000u) ? ~u : (u | 0x80000000u);
}
// flag=0: 4-byte elements (int32 OR float32 bools); flag=1: 1-byte elements
__device__ __forceinline__ int mask_ok(const void* al, int fl, size_t idx) {
    if (fl) return ((const unsigned char*)al)[idx] != 0;
    return ((const unsigned*)al)[idx] != 0u;
}

__device__ __forceinline__ float blk_max(float x, float* scr) {
#pragma unroll
    for (int o = 32; o > 0; o >>= 1) x = fmaxf(x, __shfl_xor(x, o));
    __syncthreads();
    if ((threadIdx.x & 63) == 0) scr[threadIdx.x >> 6] = x;
    __syncthreads();
    return fmaxf(fmaxf(scr[0], scr[1]), fmaxf(scr[2], scr[3]));
}
__device__ __forceinline__ float blk_sum(float x, float* scr) {
#pragma unroll
    for (int o = 32; o > 0; o >>= 1) x += __shfl_xor(x, o);
    __syncthreads();
    if ((threadIdx.x & 63) == 0) scr[threadIdx.x >> 6] = x;
    __syncthreads();
    return scr[0] + scr[1] + scr[2] + scr[3];
}

// -------- detect allowed element width --------------------------------------
__global__ void detect_k(const unsigned* __restrict__ a, int* __restrict__ flag) {
    int bad = 0;
    for (int i = threadIdx.x; i < 4096; i += 256) {
        unsigned w = a[i];
        if (w != 0u && w != 1u && w != 0x3F800000u) bad = 1;
    }
    if (bad) *flag = 1;
}

// -------- pack allowed into a 32 MB bitmask ---------------------------------
__global__ __launch_bounds__(256) void pack_k(const void* __restrict__ allowed,
                                              const int* __restrict__ flag,
                                              unsigned long long* __restrict__ pk) {
    const int fl = *flag;
    const size_t nwords = ((size_t)N_DIM * N_DIM) >> 6;
    const int lane = threadIdx.x & 63;
    const size_t wave = (((size_t)blockIdx.x * 256 + threadIdx.x) >> 6);
    const size_t nwave = ((size_t)gridDim.x * 256) >> 6;
    for (size_t w = wave; w < nwords; w += nwave) {
        size_t idx = (w << 6) + (size_t)lane;
        int nz;
        if (fl) nz = ((const unsigned char*)allowed)[idx] != 0;
        else    nz = ((const unsigned*)allowed)[idx] != 0u;
        unsigned long long m = __ballot(nz);
        if (lane == 0) pk[w] = m;
    }
}

// -------- per-row top-128 + log_softmax; survivor fast-path -----------------
__global__ __launch_bounds__(256) void topk_lsm_k(const float* __restrict__ U,
                                                  int* __restrict__ candg,
                                                  float* __restrict__ lsmg) {
    const int t = blockIdx.x;
    const float* row = U + (size_t)t * N_DIM;
    __shared__ unsigned hist[256];
    __shared__ int sel[2];
    __shared__ int cnts[4];   // [0]=taken [1]=survA [2]=survB [3]=eq-take
    __shared__ float vals[128];
    __shared__ int inds[128];
    __shared__ float sva[SCAP]; __shared__ int sia[SCAP];
    __shared__ float svb[SCAP]; __shared__ int sib[SCAP];
    __shared__ float scr[4];
    const int tid = threadIdx.x;
    // ---- pass 0: full-row histogram of top-8 key bits ----
    hist[tid] = 0;
    if (tid < 4) cnts[tid] = 0;
    if (tid < 128) { vals[tid] = -1.0e30f; inds[tid] = 0; }
    __syncthreads();
    for (int i = tid; i < N_DIM; i += 256)
        atomicAdd(&hist[fkey(row[i]) >> 24], 1u);
    __syncthreads();
    if (tid == 0) {
        int acc = 0, d = 0;
        for (int dig = 255; dig >= 0; --dig) {
            int c = (int)hist[dig];
            if (acc + c >= 128) { d = dig; break; }
            acc += c;
        }
        sel[0] = d; sel[1] = acc;
    }
    __syncthreads();
    const int d0 = sel[0];
    const int c0 = (int)hist[d0];
    if (c0 <= SCAP) {
        // ===== fast path: collect greats + survivors in ONE more full read ==
        for (int i = tid; i < N_DIM; i += 256) {
            float f = row[i];
            int b = (int)(fkey(f) >> 24);
            if (b > d0) {
                int p = atomicAdd(&cnts[0], 1);
                if (p < 128) { vals[p] = f; inds[p] = i; }
            } else if (b == d0) {
                int p = atomicAdd(&cnts[1], 1);
                sva[p] = f; sia[p] = i;
            }
        }
        __syncthreads();
        float* sv = sva; int* si = sia; float* dv = svb; int* di = sib;
        int scnt = cnts[1];
        for (int pass = 1; pass < 4; ++pass) {
            const int sh = 24 - pass * 8;
            hist[tid] = 0;
            if (tid == 0) cnts[2] = 0;
            __syncthreads();
            for (int i = tid; i < scnt; i += 256)
                atomicAdd(&hist[(fkey(sv[i]) >> sh) & 255u], 1u);
            __syncthreads();
            if (tid == 0) {
                int need = 128 - cnts[0];
                int acc = 0, d = 0;
                for (int dig = 255; dig >= 0; --dig) {
                    int c = (int)hist[dig];
                    if (acc + c >= need) { d = dig; break; }
                    acc += c;
                }
                sel[0] = d;
            }
            __syncthreads();
            const int dp = sel[0];
            for (int i = tid; i < scnt; i += 256) {
                float f = sv[i];
                int dg = (int)((fkey(f) >> sh) & 255u);
                if (dg > dp) {
                    int p = atomicAdd(&cnts[0], 1);
                    if (p < 128) { vals[p] = f; inds[p] = si[i]; }
                } else if (dg == dp) {
                    int p = atomicAdd(&cnts[2], 1);
                    dv[p] = f; di[p] = si[i];
                }
            }
            __syncthreads();
            scnt = cnts[2];
            { float* tf = sv; sv = dv; dv = tf; int* ti = si; si = di; di = ti; }
            if (tid == 0) cnts[1] = scnt;   // keep visible
            __syncthreads();
        }
        const int base = min(cnts[0], 128);
        const int need = 128 - base;
        for (int i = tid; i < scnt; i += 256) {
            int p = atomicAdd(&cnts[3], 1);
            if (p < need) { vals[base + p] = sv[i]; inds[base + p] = si[i]; }
        }
        __syncthreads();
    } else {
        // ===== fallback: verified 6-pass full-scan radix select =============
        unsigned prefix = 0;
        int kneed = 128;
        for (int pass = 0; pass < 4; ++pass) {
            const int sh = 24 - pass * 8;
            hist[tid] = 0;
            __syncthreads();
            for (int i = tid; i < N_DIM; i += 256) {
                unsigned k = fkey(row[i]);
                bool match = (pass == 0) || ((k >> (sh + 8)) == prefix);
                if (match) atomicAdd(&hist[(k >> sh) & 255u], 1u);
            }
            __syncthreads();
            if (tid == 0) {
                int acc = 0, d = 0;
                for (int dig = 255; dig >= 0; --dig) {
                    int c = (int)hist[dig];
                    if (acc + c >= kneed) { d = dig; break; }
                    acc += c;
                }
                sel[0] = d; sel[1] = acc;
            }
            __syncthreads();
            kneed -= sel[1];
            prefix = (prefix << 8) | (unsigned)sel[0];
            __syncthreads();
        }
        const unsigned K = prefix;
        if (tid < 4) cnts[tid] = 0;
        __syncthreads();
        for (int i = tid; i < N_DIM; i += 256) {
            float f = row[i];
            unsigned k = fkey(f);
            if (k > K) { int p = atomicAdd(&cnts[0], 1); if (p < 128) { vals[p] = f; inds[p] = i; } }
        }
        __syncthreads();
        const int cgt = min(cnts[0], 128);
        for (int i = tid; i < N_DIM; i += 256) {
            float f = row[i];
            unsigned k = fkey(f);
            if (k == K) {
                int p = atomicAdd(&cnts[1], 1);
                if (cgt + p < 128) { vals[cgt + p] = f; inds[cgt + p] = i; }
            }
        }
        __syncthreads();
    }
    // ---- log_softmax over the 128 selected ----
    float xv = (tid < 128) ? vals[tid] : -3.0e38f;
    float mx = blk_max(xv, scr);
    float ex = (tid < 128) ? __expf(vals[tid] - mx) : 0.f;
    float sm = blk_sum(ex, scr);
    float lse = mx + __logf(fmaxf(sm, 1e-37f));
    if (tid < 128) {
        candg[t * 128 + tid] = min(max(inds[tid], 0), N_DIM - 1);
        lsmg[t * 128 + tid] = vals[tid] - lse;
    }
}

// -------- cast H to bf16 ----------------------------------------------------
__global__ void cast_h_k(const float* __restrict__ H, u16* __restrict__ Hbf) {
    size_t base = ((size_t)blockIdx.x * 256 + threadIdx.x) * 4;
    float4 f = *(const float4*)(H + base);
    ushort4 o;
    o.x = f2bf(f.x); o.y = f2bf(f.y); o.z = f2bf(f.z); o.w = f2bf(f.w);
    *(ushort4*)(Hbf + base) = o;
}

// -------- HW = H @ W (fp32 VALU, bf16 out) ----------------------------------
__global__ __launch_bounds__(256) void gemm_hw_k(const float* __restrict__ H,
                                                 const float* __restrict__ W,
                                                 u16* __restrict__ HWbf) {
    const int r0 = blockIdx.x * 8;
    __shared__ float Hl[8][512];
    for (int idx = threadIdx.x; idx < 8 * 512; idx += 256) {
        int r = idx >> 9, k = idx & 511;
        Hl[r][k] = H[(size_t)(r0 + r) * 512 + k];
    }
    __syncthreads();
    const int c = threadIdx.x;
    float acc0[8], acc1[8];
#pragma unroll
    for (int r = 0; r < 8; ++r) { acc0[r] = 0.f; acc1[r] = 0.f; }
    for (int k = 0; k < 512; ++k) {
        float w0 = W[(size_t)k * 512 + c];
        float w1 = W[(size_t)k * 512 + c + 256];
#pragma unroll
        for (int r = 0; r < 8; ++r) {
            float h = Hl[r][k];
            acc0[r] += h * w0;
            acc1[r] += h * w1;
        }
    }
#pragma unroll
    for (int r = 0; r < 8; ++r) {
        HWbf[(size_t)(r0 + r) * 512 + c] = f2bf(acc0[r]);
        HWbf[(size_t)(r0 + r) * 512 + c + 256] = f2bf(acc1[r]);
    }
}

// -------- pair step t: MFMA matmul -> log-domain fp32 M directly ------------
// M_t[i][j] = dot(HW[prev_i], H[cur_j]) + (allowed ? 0 : PEN) + lsm_t[j]
__global__ __launch_bounds__(256) void pair_k(const int* __restrict__ candg,
                                              const float* __restrict__ lsmg,
                                              const u16* __restrict__ HWbf,
                                              const u16* __restrict__ Hbf,
                                              const void* __restrict__ allowed,
                                              const int* __restrict__ flag,
                                              const unsigned* __restrict__ pk,
                                              float* __restrict__ M0) {
    const int t = blockIdx.x + 1;
    __shared__ u16 Ash[128][40];
    __shared__ u16 Bsh[128][40];
    __shared__ int sprev[128], scur[128];
    __shared__ float slsm[128];
    const int tid = threadIdx.x, lane = tid & 63, wv = tid >> 6;
    const int jlo = lane & 15, quad = lane >> 4;
    if (tid < 128) {
        sprev[tid] = min(max(candg[(t - 1) * 128 + tid], 0), N_DIM - 1);
        scur[tid]  = min(max(candg[t * 128 + tid], 0), N_DIM - 1);
        slsm[tid]  = lsmg[(size_t)t * 128 + tid];
    }
    __syncthreads();
    f4v acc[2][8];
#pragma unroll
    for (int a = 0; a < 2; ++a)
#pragma unroll
        for (int b = 0; b < 8; ++b) acc[a][b] = (f4v){0.f, 0.f, 0.f, 0.f};
    const int rr = tid >> 2, kk = (tid & 3) * 8;
    for (int kc = 0; kc < 16; ++kc) {
        const int k0 = kc * 32;
        *(s8v*)&Ash[rr][kk]      = *(const s8v*)(HWbf + (size_t)sprev[rr] * 512 + k0 + kk);
        *(s8v*)&Ash[rr + 64][kk] = *(const s8v*)(HWbf + (size_t)sprev[rr + 64] * 512 + k0 + kk);
        *(s8v*)&Bsh[rr][kk]      = *(const s8v*)(Hbf + (size_t)scur[rr] * 512 + k0 + kk);
        *(s8v*)&Bsh[rr + 64][kk] = *(const s8v*)(Hbf + (size_t)scur[rr + 64] * 512 + k0 + kk);
        __syncthreads();
        s8v a0 = *(const s8v*)&Ash[wv * 32 + jlo][quad * 8];
        s8v a1 = *(const s8v*)&Ash[wv * 32 + 16 + jlo][quad * 8];
#pragma unroll
        for (int ct = 0; ct < 8; ++ct) {
            s8v b = *(const s8v*)&Bsh[ct * 16 + jlo][quad * 8];
            acc[0][ct] = mfma16(a0, b, acc[0][ct]);
            acc[1][ct] = mfma16(a1, b, acc[1][ct]);
        }
        __syncthreads();
    }
    const int fl = *flag;
    int pis[2][4];
#pragma unroll
    for (int rt = 0; rt < 2; ++rt)
#pragma unroll
        for (int r = 0; r < 4; ++r)
            pis[rt][r] = sprev[wv * 32 + rt * 16 + quad * 4 + r];
    float* Mo = M0 + (size_t)(t - 1) * 16384;
#pragma unroll
    for (int ct = 0; ct < 8; ++ct) {
        const int j = ct * 16 + jlo;
        const int cj = scur[j];
        const float lj = slsm[j];
#pragma unroll
        for (int rt = 0; rt < 2; ++rt)
#pragma unroll
            for (int r = 0; r < 4; ++r) {
                const int pi = pis[rt][r];
                int ok;
                if (pk) {
                    unsigned wd = pk[(size_t)cj * 512 + (pi >> 5)];
                    ok = (wd >> (pi & 31)) & 1;
                } else {
                    ok = mask_ok(allowed, fl, (size_t)cj * N_DIM + (size_t)pi);
                }
                const int i = wv * 32 + rt * 16 + quad * 4 + r;
                float d = acc[rt][ct][r] + lj;
                if (!ok) d += PEN;
                Mo[(size_t)i * 128 + j] = d;
            }
    }
}

// -------- gold path scores --------------------------------------------------
__global__ __launch_bounds__(256) void score_k(const float* __restrict__ U,
                                               const int* __restrict__ gold,
                                               const void* __restrict__ allowed,
                                               const int* __restrict__ flag,
                                               const u16* __restrict__ HWbf,
                                               const u16* __restrict__ Hbf,
                                               float* __restrict__ accums) {
    const int t = blockIdx.x;
    __shared__ float scr[4];
    float part = 0.f;
    int gp = 0, gc = 0;
    if (t < L_DIM - 1) {
        gp = min(max(gold[t], 0), N_DIM - 1);
        gc = min(max(gold[t + 1], 0), N_DIM - 1);
        const u16* ar = HWbf + (size_t)gp * 512;
        const u16* br = Hbf + (size_t)gc * 512;
        for (int k = threadIdx.x; k < 512; k += 256)
            part += b2f(ar[k]) * b2f(br[k]);
    }
    float tot = blk_sum(part, scr);
    if (threadIdx.x == 0) {
        if (t < L_DIM - 1) {
            int ok = mask_ok(allowed, *flag, (size_t)gc * N_DIM + (size_t)gp);
            atomicAdd(&accums[1], ok ? tot : PEN);
        }
        int g0 = min(max(gold[t], 0), N_DIM - 1);
        atomicAdd(&accums[0], U[(size_t)t * N_DIM + g0]);
    }
}

// -------- log-domain fp32 tree combine (r6-verified) ------------------------
__global__ __launch_bounds__(256) void comb_k(const float* __restrict__ Min,
                                              float* __restrict__ Mout, int n_in) {
    const int o = blockIdx.x, rs = blockIdx.y;
    const int tid = threadIdx.x;
    const float* A = Min + (size_t)(2 * o) * 16384;
    float* C = Mout + (size_t)o * 16384;
    if (2 * o + 1 >= n_in) {
        for (int idx = tid; idx < 64 * 128; idx += 256) {
            int i = rs * 64 + (idx >> 7), k = idx & 127;
            C[(size_t)i * 128 + k] = A[(size_t)i * 128 + k];
        }
        return;
    }
    __shared__ float At[128][64];
    __shared__ float Bs[128 * 128];
    const float* B = Min + (size_t)(2 * o + 1) * 16384;
    for (int idx = tid; idx < 64 * 128; idx += 256) {
        int il = idx & 63, j = idx >> 6;
        At[j][il] = A[(size_t)(rs * 64 + il) * 128 + j];
    }
    for (int idx = tid; idx < 16384; idx += 256) Bs[idx] = B[idx];
    __syncthreads();
    const int i0 = (tid & 15) * 4, k0 = (tid >> 4) * 8;
    float m[4][8], s[4][8];
#pragma unroll
    for (int a = 0; a < 4; ++a)
#pragma unroll
        for (int b = 0; b < 8; ++b) m[a][b] = -3.0e38f;
    for (int j = 0; j < 128; ++j) {
        float4 av = *(const float4*)&At[j][i0];
        float4 b0 = *(const float4*)&Bs[j * 128 + k0];
        float4 b1 = *(const float4*)&Bs[j * 128 + k0 + 4];
        float aa[4] = {av.x, av.y, av.z, av.w};
        float bb[8] = {b0.x, b0.y, b0.z, b0.w, b1.x, b1.y, b1.z, b1.w};
#pragma unroll
        for (int a = 0; a < 4; ++a)
#pragma unroll
            for (int b = 0; b < 8; ++b) m[a][b] = fmaxf(m[a][b], aa[a] + bb[b]);
    }
#pragma unroll
    for (int a = 0; a < 4; ++a)
#pragma unroll
        for (int b = 0; b < 8; ++b) s[a][b] = 0.f;
    for (int j = 0; j < 128; ++j) {
        float4 av = *(const float4*)&At[j][i0];
        float4 b0 = *(const float4*)&Bs[j * 128 + k0];
        float4 b1 = *(const float4*)&Bs[j * 128 + k0 + 4];
        float aa[4] = {av.x, av.y, av.z, av.w};
        float bb[8] = {b0.x, b0.y, b0.z, b0.w, b1.x, b1.y, b1.z, b1.w};
#pragma unroll
        for (int a = 0; a < 4; ++a)
#pragma unroll
            for (int b = 0; b < 8; ++b) s[a][b] += __expf(aa[a] + bb[b] - m[a][b]);
    }
#pragma unroll
    for (int a = 0; a < 4; ++a)
#pragma unroll
        for (int b = 0; b < 8; ++b)
            C[(size_t)(rs * 64 + i0 + a) * 128 + k0 + b] = m[a][b] + __logf(s[a][b]);
}

// -------- final: alpha0 through 8 log-matrices, online LSE ------------------
__global__ __launch_bounds__(256) void tfinal_k(const float* __restrict__ M7,
                                                const float* __restrict__ lsmg,
                                                const float* __restrict__ accums,
                                                float* __restrict__ out) {
    __shared__ float v[128];
    __shared__ float pm[2][128], ps[2][128];
    __shared__ float scr[4];
    const int tid = threadIdx.x;
    const int k = tid & 127, h = tid >> 7;
    if (tid < 128) v[tid] = lsmg[tid];
    __syncthreads();
    for (int s = 0; s < 8; ++s) {
        const float* M = M7 + (size_t)s * 16384 + (size_t)h * 64 * 128 + k;
        const float* vh = &v[h * 64];
        float m = -3.0e38f, sum = 0.f;
#pragma unroll 8
        for (int i = 0; i < 64; ++i) {
            float a = vh[i] + M[(size_t)i * 128];
            float nm = fmaxf(m, a);
            sum = sum * __expf(m - nm) + __expf(a - nm);
            m = nm;
        }
        pm[h][k] = m; ps[h][k] = sum;
        __syncthreads();
        if (tid < 128) {
            float m0 = pm[0][tid], m1 = pm[1][tid];
            float mm = fmaxf(m0, m1);
            float ss = ps[0][tid] * __expf(m0 - mm) + ps[1][tid] * __expf(m1 - mm);
            v[tid] = mm + __logf(ss);   // ss >= 1
        }
        __syncthreads();
    }
    float x = (tid < 128) ? v[tid] : -3.0e38f;
    float mz = blk_max(x, scr);
    float e = (tid < 128) ? __expf(v[tid] - mz) : 0.f;
    float sm = blk_sum(e, scr);
    if (tid == 0) out[0] = mz + __logf(fmaxf(sm, 1e-37f)) - (accums[0] + accums[1]);
}

extern "C" void kernel_launch(void* const* d_in, const int* in_sizes, int n_in,
                              void* d_out, int out_size, void* d_ws, size_t ws_size,
                              hipStream_t stream) {
    const float* U = (const float*)d_in[0];
    const float* H = (const float*)d_in[1];
    const float* W = (const float*)d_in[2];
    const int* gold = (const int*)d_in[3];
    const void* allowed = (const void*)d_in[4];

    char* ws = (char*)d_ws;
    float* accums = (float*)ws;
    int* flag = (int*)(ws + 8);
    size_t off = 256;
    int* cand = (int*)(ws + off);     off += (size_t)L_DIM * R_DIM * 4;
    float* lsm = (float*)(ws + off);  off += (size_t)L_DIM * R_DIM * 4;
    u16* Hbf = (u16*)(ws + off);      off += (size_t)N_DIM * 512 * 2;
    u16* HWbf = (u16*)(ws + off);     off += (size_t)N_DIM * 512 * 2;
    unsigned long long* pk64 = nullptr;
    const size_t pk_bytes = ((size_t)N_DIM * N_DIM) / 8;
    // tree matrices: 1023 + 512 + 256 + 128 + 64 + 32 + 16 + 8 (fp32 64 KB each)
    static const int lvl_n[8] = {1023, 512, 256, 128, 64, 32, 16, 8};
    float* M[8];
    size_t treesz = 0;
    for (int l = 0; l < 8; ++l) treesz += (size_t)lvl_n[l] * 16384 * 4;
    if (ws_size >= off + pk_bytes + treesz) {
        pk64 = (unsigned long long*)(ws + off); off += pk_bytes;
    }
    for (int l = 0; l < 8; ++l) { M[l] = (float*)(ws + off); off += (size_t)lvl_n[l] * 16384 * 4; }

    hipMemsetAsync(d_ws, 0, 256, stream);
    detect_k<<<1, 256, 0, stream>>>((const unsigned*)d_in[4], flag);
    topk_lsm_k<<<L_DIM, 256, 0, stream>>>(U, cand, lsm);
    cast_h_k<<<(N_DIM * 512) / (256 * 4), 256, 0, stream>>>(H, Hbf);
    gemm_hw_k<<<N_DIM / 8, 256, 0, stream>>>(H, W, HWbf);
    if (pk64) pack_k<<<1024, 256, 0, stream>>>(allowed, flag, pk64);
    pair_k<<<L_DIM - 1, 256, 0, stream>>>(cand, lsm, HWbf, Hbf, allowed, flag,
                                          (const unsigned*)pk64, M[0]);
    score_k<<<L_DIM, 256, 0, stream>>>(U, gold, allowed, flag, HWbf, Hbf, accums);
    for (int l = 0; l < 7; ++l)
        comb_k<<<dim3(lvl_n[l + 1], 2), 256, 0, stream>>>(M[l], M[l + 1], lvl_n[l]);
    tfinal_k<<<1, 256, 0, stream>>>(M[7], lsm, accums, (float*)d_out);
}